// Round 1
// baseline (196.673 us; speedup 1.0000x reference)
//
#include <hip/hip_runtime.h>
#include <hip/hip_bf16.h>

#define FH 240
#define FIT_IN 1600
#define NK 2048            // table knots per e
#define TLO -16.0f
#define TINVH 64.0f        // knots per unit S (h = 1/64)
#define KSPLIT0 8
#define CHUNK0 200

typedef _Float16 h8 __attribute__((ext_vector_type(8)));
typedef float f4v __attribute__((ext_vector_type(4)));

__device__ __forceinline__ float fast_tanh(float x) {
    float e2 = __builtin_amdgcn_exp2f(x * 2.8853900817779268f);
    return 1.0f - 2.0f * __builtin_amdgcn_rcpf(e2 + 1.0f);
}

#define FMA_ROW(r, s) \
    acc[r][0] += (s) * b0.x; acc[r][1] += (s) * b0.y; \
    acc[r][2] += (s) * b0.z; acc[r][3] += (s) * b0.w; \
    acc[r][4] += (s) * b1.x; acc[r][5] += (s) * b1.y; \
    acc[r][6] += (s) * b1.z; acc[r][7] += (s) * b1.w;

// ---------------------------------------------------------------------------
// k_table: piecewise-linear table T[e][knot][100] of the embedding MLP.
// (unchanged)
// ---------------------------------------------------------------------------
#define TOFF_W0   0
#define TOFF_B0   28
#define TOFF_B1   56
#define TOFF_B2   108
#define TOFF_W1   208
#define TOFF_W2   1508
#define TOFF_H0T  6708
#define TOFF_H1T  10008
#define TSMEM     16608

__global__ __launch_bounds__(256) void k_table(
    const float* __restrict__ eW0, const float* __restrict__ eB0,
    const float* __restrict__ eW1, const float* __restrict__ eB1,
    const float* __restrict__ eW2, const float* __restrict__ eB2,
    float* __restrict__ T)
{
    __shared__ float sm[TSMEM];

    const int t    = threadIdx.x;
    const int w    = t >> 6;
    const int lane = t & 63;
    const int mi   = lane & 7;
    const int gi   = lane >> 3;
    const int mrow = w * 32 + mi * 4;

    const int e  = blockIdx.y;
    const int k0 = blockIdx.x * 128;

    for (int idx = t; idx < 1250; idx += 256) {
        int k = idx / 50, g = idx - k * 50;
        sm[TOFF_W1 + k * 52 + g] = eW1[e * 1250 + idx];
    }
    for (int idx = t; idx < 5000; idx += 256) {
        int k = idx / 100, r = idx - k * 100;
        int half = r / 50, g = r - half * 50;
        sm[TOFF_W2 + k * 104 + half * 52 + g] = eW2[e * 5000 + idx];
    }
    if (t < 25)       { sm[TOFF_W0 + t] = eW0[e * 25 + t]; sm[TOFF_B0 + t] = eB0[e * 25 + t]; }
    else if (t < 75)  { sm[TOFF_B1 + (t - 25)] = eB1[e * 50 + (t - 25)]; }
    else if (t < 175) { sm[TOFF_B2 + (t - 75)] = eB2[e * 100 + (t - 75)]; }
    __syncthreads();

    if (t < 128) {
        const float S = TLO + (float)(k0 + t) * (1.0f / TINVH);
        #pragma unroll
        for (int k = 0; k < 25; ++k)
            sm[TOFF_H0T + k * 132 + t] = fast_tanh(S * sm[TOFF_W0 + k] + sm[TOFF_B0 + k]);
    }
    __syncthreads();

    {
        float acc[4][8];
        #pragma unroll
        for (int r = 0; r < 4; ++r)
            #pragma unroll
            for (int c = 0; c < 8; ++c) acc[r][c] = 0.f;

        #pragma unroll 5
        for (int k = 0; k < 25; ++k) {
            const float4 av = *(const float4*)&sm[TOFF_H0T + k * 132 + mrow];
            const float4 b0 = *(const float4*)&sm[TOFF_W1 + k * 52 + gi * 8];
            const float4 b1 = *(const float4*)&sm[TOFF_W1 + k * 52 + gi * 8 + 4];
            FMA_ROW(0, av.x) FMA_ROW(1, av.y) FMA_ROW(2, av.z) FMA_ROW(3, av.w)
        }
        #pragma unroll
        for (int c = 0; c < 8; ++c) {
            const int g = gi * 8 + c;
            if (g < 50) {
                const int gm = (g < 25) ? g : g - 25;
                const float4 h0r = *(const float4*)&sm[TOFF_H0T + gm * 132 + mrow];
                const float bias = sm[TOFF_B1 + g];
                float4 o;
                o.x = fast_tanh(acc[0][c] + bias) + h0r.x;
                o.y = fast_tanh(acc[1][c] + bias) + h0r.y;
                o.z = fast_tanh(acc[2][c] + bias) + h0r.z;
                o.w = fast_tanh(acc[3][c] + bias) + h0r.w;
                *(float4*)&sm[TOFF_H1T + g * 132 + mrow] = o;
            }
        }
    }
    __syncthreads();

    for (int half = 0; half < 2; ++half) {
        float acc[4][8];
        #pragma unroll
        for (int r = 0; r < 4; ++r)
            #pragma unroll
            for (int c = 0; c < 8; ++c) acc[r][c] = 0.f;

        #pragma unroll 5
        for (int k = 0; k < 50; ++k) {
            const float4 av = *(const float4*)&sm[TOFF_H1T + k * 132 + mrow];
            const float4 b0 = *(const float4*)&sm[TOFF_W2 + k * 104 + half * 52 + gi * 8];
            const float4 b1 = *(const float4*)&sm[TOFF_W2 + k * 104 + half * 52 + gi * 8 + 4];
            FMA_ROW(0, av.x) FMA_ROW(1, av.y) FMA_ROW(2, av.z) FMA_ROW(3, av.w)
        }
        #pragma unroll
        for (int c = 0; c < 8; ++c) {
            const int g = gi * 8 + c;
            if (g < 50) {
                const float4 h1r = *(const float4*)&sm[TOFF_H1T + g * 132 + mrow];
                const float bias = sm[TOFF_B2 + half * 50 + g];
                float* out = T + ((size_t)e * NK + k0 + mrow) * 100 + half * 50 + g;
                out[0]   = fast_tanh(acc[0][c] + bias) + h1r.x;
                out[100] = fast_tanh(acc[1][c] + bias) + h1r.y;
                out[200] = fast_tanh(acc[2][c] + bias) + h1r.z;
                out[300] = fast_tanh(acc[3][c] + bias) + h1r.w;
            }
        }
    }
}

// ---------------------------------------------------------------------------
// k_cvt: f32 weights -> f16 TRANSPOSED WT[tp][n][k] for the three fit layers.
// (unchanged)
// ---------------------------------------------------------------------------
__global__ __launch_bounds__(256) void k_cvt(
    const float* __restrict__ fW0, const float* __restrict__ fW1,
    const float* __restrict__ fW2,
    _Float16* __restrict__ W0T, _Float16* __restrict__ W1T,
    _Float16* __restrict__ W2T)
{
    const int total = 768000 + 115200 + 115200;
    for (int idx = blockIdx.x * 256 + threadIdx.x; idx < total; idx += gridDim.x * 256) {
        if (idx < 768000) {
            const int tp = idx / 384000, r = idx - tp * 384000;
            const int n = r / 1600, k = r - n * 1600;
            W0T[idx] = (_Float16)fW0[tp * 384000 + k * 240 + n];
        } else if (idx < 883200) {
            const int j = idx - 768000;
            const int tp = j / 57600, r = j - tp * 57600;
            const int n = r / 240, k = r - n * 240;
            W1T[j] = (_Float16)fW1[tp * 57600 + k * 240 + n];
        } else {
            const int j = idx - 883200;
            const int tp = j / 57600, r = j - tp * 57600;
            const int n = r / 240, k = r - n * 240;
            W2T[j] = (_Float16)fW2[tp * 57600 + k * 240 + n];
        }
    }
}

// ---------------------------------------------------------------------------
// k_xyz: per atom: gather+lerp G from table, reduce xyz[c][g], emit DR (f16).
// (unchanged)
// ---------------------------------------------------------------------------
__global__ __launch_bounds__(256) void k_xyz(
    const float* __restrict__ Ri, const float* __restrict__ T,
    _Float16* __restrict__ DRh)
{
    __shared__ float4 sR[256];
    __shared__ float  sF[256];
    __shared__ int    sI[256];
    __shared__ float  sXYZ[400];

    const int t   = threadIdx.x;
    const int blk = blockIdx.x;          // 0..2047
    const int b   = blk >> 9;
    const int i   = (blk >> 8) & 1;
    const int n   = blk & 255;

    for (int idx = t; idx < 400; idx += 256) sXYZ[idx] = 0.f;

    {
        const int jj = t >> 7, m = t & 127;
        const size_t row = ((size_t)(b * 512 + i * 256 + n)) * 256 + jj * 128 + m;
        const float4 r = *(const float4*)(Ri + row * 4);
        sR[t] = r;
        float u = (r.x - TLO) * TINVH;
        int ii = (int)u;
        ii = (ii < 0) ? 0 : ((ii > NK - 2) ? NK - 2 : ii);
        sI[t] = ii;
        sF[t] = u - (float)ii;
    }
    __syncthreads();

    const int jj = t >> 7;
    const int g  = t & 127;
    if (g < 100) {
        const float* Te = T + ((size_t)(i * 2 + jj)) * NK * 100 + g;
        float a0 = 0.f, a1 = 0.f, a2 = 0.f, a3 = 0.f;
        #pragma unroll 4
        for (int m = 0; m < 128; ++m) {
            const int s = jj * 128 + m;
            const float4 R = sR[s];
            const float  f = sF[s];
            const float* p = Te + (size_t)sI[s] * 100;
            const float v0 = p[0], v1 = p[100];
            const float G = v0 + f * (v1 - v0);
            a0 += R.x * G; a1 += R.y * G; a2 += R.z * G; a3 += R.w * G;
        }
        atomicAdd(&sXYZ[g],       a0);
        atomicAdd(&sXYZ[100 + g], a1);
        atomicAdd(&sXYZ[200 + g], a2);
        atomicAdd(&sXYZ[300 + g], a3);
    }
    __syncthreads();

    const float inv = 1.0f / 65536.0f;
    _Float16* dr = DRh + (((size_t)i * 4 + b) * 256 + n) * FIT_IN;
    for (int q = t; q < 400; q += 256) {
        const int gg = q >> 2, h0 = (q & 3) * 4;
        ushort4 pk;
        _Float16* ph = (_Float16*)&pk;
        #pragma unroll
        for (int r = 0; r < 4; ++r) {
            const int h = h0 + r;
            const float v = (sXYZ[gg] * sXYZ[h] + sXYZ[100 + gg] * sXYZ[100 + h]
                           + sXYZ[200 + gg] * sXYZ[200 + h] + sXYZ[300 + gg] * sXYZ[300 + h]) * inv;
            ph[r] = (_Float16)v;
        }
        *(ushort4*)(dr + gg * 16 + h0) = pk;
    }
}

// ---------------------------------------------------------------------------
// k_fit_mfma: layer-0 partial GEMM P[ks] = A[rows, kslice] @ W[kslice, 240].
// 32-row M-tiles (grid 64 x KSPLIT0 = 512 blocks => 2 blocks/CU overlap).
// Verified layouts: A[m=lane&15][k=quad*8+j], B[k=quad*8+j][n=lane&15],
// D[row=quad*4+reg][col=lane&15].
// ---------------------------------------------------------------------------
template<int K, int CHUNK>
__global__ __launch_bounds__(256) void k_fit_mfma(
    const _Float16* __restrict__ A, const _Float16* __restrict__ WT,
    float* __restrict__ P)
{
    __shared__ _Float16 sA[32 * 40];     // [m][k] stride 40
    __shared__ _Float16 sBT[240 * 40];   // [n][k] stride 40

    const int t    = threadIdx.x;
    const int w    = t >> 6;
    const int lane = t & 63;
    const int ln   = lane & 15;
    const int quad = lane >> 4;

    const int mtile = blockIdx.x;        // 0..63
    const int ks    = blockIdx.y;
    const int row0  = mtile * 32;
    const int tp    = mtile >> 5;
    const int kbeg  = ks * CHUNK;
    const int kend  = (kbeg + CHUNK < K) ? (kbeg + CHUNK) : K;
    const int nf0   = w * 4;
    const int nfrags = (w < 3) ? 4 : 3;

    f4v acc[2][4];
    #pragma unroll
    for (int mf = 0; mf < 2; ++mf)
        #pragma unroll
        for (int nf = 0; nf < 4; ++nf) acc[mf][nf] = (f4v)0.f;

    const _Float16* Ab = A + (size_t)row0 * K;
    const _Float16* Wb = WT + (size_t)tp * 240 * K;

    for (int k0 = kbeg; k0 < kend; k0 += 32) {
        // stage A tile 32x32 (one uint2 = 4 f16 per thread)
        {
            const int m = t >> 3, kq = (t & 7) * 4;
            const int k = k0 + kq;
            uint2 v = make_uint2(0u, 0u);
            if (k < kend) v = *(const uint2*)(Ab + (size_t)m * K + k);
            *(uint2*)&sA[m * 40 + kq] = v;
        }
        // stage W tile 240x32 from transposed WT (coalesced)
        for (int q = t; q < 1920; q += 256) {
            const int n = q >> 3, kq = (q & 7) * 4;
            const int k = k0 + kq;
            uint2 v = make_uint2(0u, 0u);
            if (k < kend) v = *(const uint2*)(Wb + (size_t)n * K + k);
            *(uint2*)&sBT[n * 40 + kq] = v;
        }
        __syncthreads();

        h8 afr[2];
        #pragma unroll
        for (int mf = 0; mf < 2; ++mf)
            afr[mf] = *(const h8*)&sA[(mf * 16 + ln) * 40 + quad * 8];
        #pragma unroll
        for (int nf = 0; nf < 4; ++nf) {
            if (nf < nfrags) {
                const h8 bfr = *(const h8*)&sBT[((nf0 + nf) * 16 + ln) * 40 + quad * 8];
                #pragma unroll
                for (int mf = 0; mf < 2; ++mf)
                    acc[mf][nf] = __builtin_amdgcn_mfma_f32_16x16x32_f16(
                        afr[mf], bfr, acc[mf][nf], 0, 0, 0);
            }
        }
        __syncthreads();
    }

    float* Pb = P + ((size_t)ks * 2048 + row0) * FH;
    #pragma unroll
    for (int nf = 0; nf < 4; ++nf) {
        if (nf < nfrags) {
            const int col = (nf0 + nf) * 16 + ln;
            #pragma unroll
            for (int mf = 0; mf < 2; ++mf)
                #pragma unroll
                for (int r = 0; r < 4; ++r) {
                    const int row = mf * 16 + quad * 4 + r;
                    Pb[(size_t)row * FH + col] = acc[mf][nf][r];
                }
        }
    }
}

// ---------------------------------------------------------------------------
// k_fit_tail: per 16 rows, does EVERYTHING after the layer-0 partial GEMM:
//   h0 = tanh(sum_ks P + b0)           (KSPLIT0 reduce, f32 LDS + f16 LDS A)
//   h1 = tanh(h0 @ W1 + b1) + h0       (MFMA 16x16x32, K=240 padded to 256)
//   h2 = tanh(h1 @ W2 + b2) + h1
//   out = h2 . W3 + b3
// Replaces 6 kernels (reduce0, mfma1, reduce1, mfma2, reduce2, out) and all
// hA/hB/hAh/hBh global round trips.
// ---------------------------------------------------------------------------
__global__ __launch_bounds__(256) void k_fit_tail(
    const float* __restrict__ P,
    const _Float16* __restrict__ W1T, const _Float16* __restrict__ W2T,
    const float* __restrict__ fb0, const float* __restrict__ fb1,
    const float* __restrict__ fb2, const float* __restrict__ fW3,
    const float* __restrict__ fb3, float* __restrict__ out)
{
    __shared__ float    hRes[2][16 * 240];  // ping-pong f32 h buffers (residual)
    __shared__ _Float16 sA[16 * 264];       // f16 A operand, k padded to 256
    __shared__ _Float16 sB[240 * 40];       // staged B tile [n][k] stride 40

    const int t    = threadIdx.x;
    const int w    = t >> 6;
    const int lane = t & 63;
    const int ln   = lane & 15;
    const int quad = lane >> 4;
    const int r0   = blockIdx.x * 16;       // global row base, 0..2032
    const int tp   = r0 >> 10;
    const int nf0  = w * 4;
    const int nfrags = (w < 3) ? 4 : 3;

    // ---- phase A: reduce P over KSPLIT0 slices, +bias, tanh -> h0 ----
    #pragma unroll
    for (int j = 0; j < 15; ++j) {
        const int e = t + j * 256;          // 0..3839, all threads full 15 iters
        const int m = e / 240, col = e - m * 240;
        const size_t base = (size_t)(r0 + m) * FH + col;
        float s = 0.f;
        #pragma unroll
        for (int ks = 0; ks < KSPLIT0; ++ks)
            s += P[(size_t)ks * 2048 * FH + base];
        const float v = fast_tanh(s + fb0[tp * FH + col]);
        hRes[0][m * 240 + col] = v;
        sA[m * 264 + col] = (_Float16)v;
    }
    // zero-pad sA k-columns 240..255
    if (t < 256) {
        const int m = t >> 4, c = 240 + (t & 15);
        sA[m * 264 + c] = (_Float16)0.f;
    }

    // ---- layers 1 and 2: 16x240 @ 240x240 MFMA + tanh + residual ----
    #pragma unroll
    for (int layer = 0; layer < 2; ++layer) {
        const _Float16* Wt = (layer == 0 ? W1T : W2T) + (size_t)tp * FH * FH;
        const float* Bias  = (layer == 0 ? fb1 : fb2) + tp * FH;
        const float* res   = hRes[layer];        // layer0 reads h0, layer1 reads h1
        float* outb        = hRes[layer ^ 1];

        f4v acc[4];
        #pragma unroll
        for (int nf = 0; nf < 4; ++nf) acc[nf] = (f4v)0.f;

        for (int k0 = 0; k0 < 256; k0 += 32) {
            __syncthreads();                     // prev-step sB reads done; sA/phase-A visible
            for (int q = t; q < 1920; q += 256) {
                const int n = q >> 3, kq = (q & 7) * 4;
                const int k = k0 + kq;
                uint2 v = make_uint2(0u, 0u);
                if (k < FH) v = *(const uint2*)(Wt + (size_t)n * FH + k);
                *(uint2*)&sB[n * 40 + kq] = v;
            }
            __syncthreads();
            const h8 afr = *(const h8*)&sA[ln * 264 + k0 + quad * 8];
            #pragma unroll
            for (int nf = 0; nf < 4; ++nf) {
                if (nf < nfrags) {
                    const h8 bfr = *(const h8*)&sB[((nf0 + nf) * 16 + ln) * 40 + quad * 8];
                    acc[nf] = __builtin_amdgcn_mfma_f32_16x16x32_f16(afr, bfr, acc[nf], 0, 0, 0);
                }
            }
        }
        __syncthreads();                         // all frag reads done before sA rewrite

        #pragma unroll
        for (int nf = 0; nf < 4; ++nf) {
            if (nf < nfrags) {
                const int col = (nf0 + nf) * 16 + ln;
                const float bias = Bias[col];
                #pragma unroll
                for (int r = 0; r < 4; ++r) {
                    const int m = quad * 4 + r;
                    const float v = fast_tanh(acc[nf][r] + bias) + res[m * 240 + col];
                    outb[m * 240 + col] = v;
                    if (layer == 0) sA[m * 264 + col] = (_Float16)v;
                }
            }
        }
        __syncthreads();                         // epilogue writes visible
    }

    // ---- out: per-row dot with W3 (h2 lives in hRes[0]) ----
    const float* h2 = hRes[0];
    const float* wv = fW3 + tp * FH;
    #pragma unroll
    for (int rr = 0; rr < 4; ++rr) {
        const int m = w * 4 + rr;
        float s = 0.f;
        for (int k = lane; k < FH; k += 64)
            s += h2[m * 240 + k] * wv[k];
        #pragma unroll
        for (int off = 32; off > 0; off >>= 1) s += __shfl_down(s, off);
        if (lane == 0) {
            const int gr = r0 + m;
            const int b = (gr >> 8) & 3, n = gr & 255;
            out[b * 512 + tp * 256 + n] = s + fb3[tp];
        }
    }
}

// ---------------------------------------------------------------------------
extern "C" void kernel_launch(void* const* d_in, const int* in_sizes, int n_in,
                              void* d_out, int out_size, void* d_ws, size_t ws_size,
                              hipStream_t stream)
{
    const float* Ri  = (const float*)d_in[0];
    const float* eW0 = (const float*)d_in[1];
    const float* eB0 = (const float*)d_in[2];
    const float* eW1 = (const float*)d_in[3];
    const float* eB1 = (const float*)d_in[4];
    const float* eW2 = (const float*)d_in[5];
    const float* eB2 = (const float*)d_in[6];
    const float* fW0 = (const float*)d_in[7];
    const float* fb0 = (const float*)d_in[8];
    const float* fW1 = (const float*)d_in[9];
    const float* fb1 = (const float*)d_in[10];
    const float* fW2 = (const float*)d_in[11];
    const float* fb2 = (const float*)d_in[12];
    const float* fW3 = (const float*)d_in[13];
    const float* fb3 = (const float*)d_in[14];

    // workspace layout (bytes)
    char* p = (char*)d_ws;
    float* T   = (float*)p;                 p += (size_t)4 * NK * 100 * 4;           // 3.28 MB
    float* P   = (float*)p;                 p += (size_t)KSPLIT0 * 2048 * FH * 4;    // 15.7 MB
    _Float16* DRh = (_Float16*)p;           p += (size_t)2048 * FIT_IN * 2;          // 6.55 MB
    _Float16* W0T = (_Float16*)p;           p += (size_t)768000 * 2;                 // 1.54 MB
    _Float16* W1T = (_Float16*)p;           p += (size_t)115200 * 2;
    _Float16* W2T = (_Float16*)p;           p += (size_t)115200 * 2;

    k_cvt<<<dim3(1024), dim3(256), 0, stream>>>(fW0, fW1, fW2, W0T, W1T, W2T);
    k_table<<<dim3(NK / 128, 4), dim3(256), 0, stream>>>(eW0, eB0, eW1, eB1, eW2, eB2, T);
    k_xyz<<<dim3(2048), dim3(256), 0, stream>>>(Ri, T, DRh);

    // layer 0 partial GEMM: K=1600, CHUNK=200, KSPLIT=8, 32-row tiles
    k_fit_mfma<FIT_IN, CHUNK0><<<dim3(64, KSPLIT0), dim3(256), 0, stream>>>(DRh, W0T, P);

    // everything else fused: reduce + layer1 + layer2 + output dot
    k_fit_tail<<<dim3(128), dim3(256), 0, stream>>>(P, W1T, W2T, fb0, fb1, fb2, fW3, fb3,
                                                    (float*)d_out);
}

// Round 2
// 174.228 us; speedup vs baseline: 1.1288x; 1.1288x over previous
//
#include <hip/hip_runtime.h>
#include <hip/hip_bf16.h>

#define FH 240
#define FIT_IN 1600
#define NK 2048            // table knots per e
#define TLO -16.0f
#define TINVH 64.0f        // knots per unit S (h = 1/64)

typedef _Float16 h8 __attribute__((ext_vector_type(8)));
typedef float f4v __attribute__((ext_vector_type(4)));

__device__ __forceinline__ float fast_tanh(float x) {
    float e2 = __builtin_amdgcn_exp2f(x * 2.8853900817779268f);
    return 1.0f - 2.0f * __builtin_amdgcn_rcpf(e2 + 1.0f);
}

#define FMA_ROW(r, s) \
    acc[r][0] += (s) * b0.x; acc[r][1] += (s) * b0.y; \
    acc[r][2] += (s) * b0.z; acc[r][3] += (s) * b0.w; \
    acc[r][4] += (s) * b1.x; acc[r][5] += (s) * b1.y; \
    acc[r][6] += (s) * b1.z; acc[r][7] += (s) * b1.w;

// ---------------------------------------------------------------------------
// k_prep: blocks 0..63 build the embedding table (old k_table, e=bid>>4,
// k0=(bid&15)*128); blocks 64..511 transpose/convert fit weights (old k_cvt).
// ---------------------------------------------------------------------------
#define TOFF_W0   0
#define TOFF_B0   28
#define TOFF_B1   56
#define TOFF_B2   108
#define TOFF_W1   208
#define TOFF_W2   1508
#define TOFF_H0T  6708
#define TOFF_H1T  10008
#define TSMEM     16608

__global__ __launch_bounds__(256) void k_prep(
    const float* __restrict__ eW0, const float* __restrict__ eB0,
    const float* __restrict__ eW1, const float* __restrict__ eB1,
    const float* __restrict__ eW2, const float* __restrict__ eB2,
    float* __restrict__ T,
    const float* __restrict__ fW0, const float* __restrict__ fW1,
    const float* __restrict__ fW2,
    _Float16* __restrict__ W0T, _Float16* __restrict__ W1T,
    _Float16* __restrict__ W2T)
{
    __shared__ float sm[TSMEM];
    const int t = threadIdx.x;

    if (blockIdx.x >= 64) {
        // ------- cvt part: grid-stride over 448 blocks -------
        const int bid0 = blockIdx.x - 64;
        const int total = 768000 + 115200 + 115200;
        for (int idx = bid0 * 256 + t; idx < total; idx += 448 * 256) {
            if (idx < 768000) {
                const int tp = idx / 384000, r = idx - tp * 384000;
                const int n = r / 1600, k = r - n * 1600;
                W0T[idx] = (_Float16)fW0[tp * 384000 + k * 240 + n];
            } else if (idx < 883200) {
                const int j = idx - 768000;
                const int tp = j / 57600, r = j - tp * 57600;
                const int n = r / 240, k = r - n * 240;
                W1T[j] = (_Float16)fW1[tp * 57600 + k * 240 + n];
            } else {
                const int j = idx - 883200;
                const int tp = j / 57600, r = j - tp * 57600;
                const int n = r / 240, k = r - n * 240;
                W2T[j] = (_Float16)fW2[tp * 57600 + k * 240 + n];
            }
        }
        return;
    }

    // ------- table part -------
    const int w    = t >> 6;
    const int lane = t & 63;
    const int mi   = lane & 7;
    const int gi   = lane >> 3;
    const int mrow = w * 32 + mi * 4;

    const int e  = blockIdx.x >> 4;
    const int k0 = (blockIdx.x & 15) * 128;

    for (int idx = t; idx < 1250; idx += 256) {
        int k = idx / 50, g = idx - k * 50;
        sm[TOFF_W1 + k * 52 + g] = eW1[e * 1250 + idx];
    }
    for (int idx = t; idx < 5000; idx += 256) {
        int k = idx / 100, r = idx - k * 100;
        int half = r / 50, g = r - half * 50;
        sm[TOFF_W2 + k * 104 + half * 52 + g] = eW2[e * 5000 + idx];
    }
    if (t < 25)       { sm[TOFF_W0 + t] = eW0[e * 25 + t]; sm[TOFF_B0 + t] = eB0[e * 25 + t]; }
    else if (t < 75)  { sm[TOFF_B1 + (t - 25)] = eB1[e * 50 + (t - 25)]; }
    else if (t < 175) { sm[TOFF_B2 + (t - 75)] = eB2[e * 100 + (t - 75)]; }
    __syncthreads();

    if (t < 128) {
        const float S = TLO + (float)(k0 + t) * (1.0f / TINVH);
        #pragma unroll
        for (int k = 0; k < 25; ++k)
            sm[TOFF_H0T + k * 132 + t] = fast_tanh(S * sm[TOFF_W0 + k] + sm[TOFF_B0 + k]);
    }
    __syncthreads();

    {
        float acc[4][8];
        #pragma unroll
        for (int r = 0; r < 4; ++r)
            #pragma unroll
            for (int c = 0; c < 8; ++c) acc[r][c] = 0.f;

        #pragma unroll 5
        for (int k = 0; k < 25; ++k) {
            const float4 av = *(const float4*)&sm[TOFF_H0T + k * 132 + mrow];
            const float4 b0 = *(const float4*)&sm[TOFF_W1 + k * 52 + gi * 8];
            const float4 b1 = *(const float4*)&sm[TOFF_W1 + k * 52 + gi * 8 + 4];
            FMA_ROW(0, av.x) FMA_ROW(1, av.y) FMA_ROW(2, av.z) FMA_ROW(3, av.w)
        }
        #pragma unroll
        for (int c = 0; c < 8; ++c) {
            const int g = gi * 8 + c;
            if (g < 50) {
                const int gm = (g < 25) ? g : g - 25;
                const float4 h0r = *(const float4*)&sm[TOFF_H0T + gm * 132 + mrow];
                const float bias = sm[TOFF_B1 + g];
                float4 o;
                o.x = fast_tanh(acc[0][c] + bias) + h0r.x;
                o.y = fast_tanh(acc[1][c] + bias) + h0r.y;
                o.z = fast_tanh(acc[2][c] + bias) + h0r.z;
                o.w = fast_tanh(acc[3][c] + bias) + h0r.w;
                *(float4*)&sm[TOFF_H1T + g * 132 + mrow] = o;
            }
        }
    }
    __syncthreads();

    for (int half = 0; half < 2; ++half) {
        float acc[4][8];
        #pragma unroll
        for (int r = 0; r < 4; ++r)
            #pragma unroll
            for (int c = 0; c < 8; ++c) acc[r][c] = 0.f;

        #pragma unroll 5
        for (int k = 0; k < 50; ++k) {
            const float4 av = *(const float4*)&sm[TOFF_H1T + k * 132 + mrow];
            const float4 b0 = *(const float4*)&sm[TOFF_W2 + k * 104 + half * 52 + gi * 8];
            const float4 b1 = *(const float4*)&sm[TOFF_W2 + k * 104 + half * 52 + gi * 8 + 4];
            FMA_ROW(0, av.x) FMA_ROW(1, av.y) FMA_ROW(2, av.z) FMA_ROW(3, av.w)
        }
        #pragma unroll
        for (int c = 0; c < 8; ++c) {
            const int g = gi * 8 + c;
            if (g < 50) {
                const float4 h1r = *(const float4*)&sm[TOFF_H1T + g * 132 + mrow];
                const float bias = sm[TOFF_B2 + half * 50 + g];
                float* out = T + ((size_t)e * NK + k0 + mrow) * 100 + half * 50 + g;
                out[0]   = fast_tanh(acc[0][c] + bias) + h1r.x;
                out[100] = fast_tanh(acc[1][c] + bias) + h1r.y;
                out[200] = fast_tanh(acc[2][c] + bias) + h1r.z;
                out[300] = fast_tanh(acc[3][c] + bias) + h1r.w;
            }
        }
    }
}

// ---------------------------------------------------------------------------
// k_xyz: per atom: gather+lerp G from table, reduce xyz[c][g], emit DR (f16).
// (unchanged — proven)
// ---------------------------------------------------------------------------
__global__ __launch_bounds__(256) void k_xyz(
    const float* __restrict__ Ri, const float* __restrict__ T,
    _Float16* __restrict__ DRh)
{
    __shared__ float4 sR[256];
    __shared__ float  sF[256];
    __shared__ int    sI[256];
    __shared__ float  sXYZ[400];

    const int t   = threadIdx.x;
    const int blk = blockIdx.x;          // 0..2047
    const int b   = blk >> 9;
    const int i   = (blk >> 8) & 1;
    const int n   = blk & 255;

    for (int idx = t; idx < 400; idx += 256) sXYZ[idx] = 0.f;

    {
        const int jj = t >> 7, m = t & 127;
        const size_t row = ((size_t)(b * 512 + i * 256 + n)) * 256 + jj * 128 + m;
        const float4 r = *(const float4*)(Ri + row * 4);
        sR[t] = r;
        float u = (r.x - TLO) * TINVH;
        int ii = (int)u;
        ii = (ii < 0) ? 0 : ((ii > NK - 2) ? NK - 2 : ii);
        sI[t] = ii;
        sF[t] = u - (float)ii;
    }
    __syncthreads();

    const int jj = t >> 7;
    const int g  = t & 127;
    if (g < 100) {
        const float* Te = T + ((size_t)(i * 2 + jj)) * NK * 100 + g;
        float a0 = 0.f, a1 = 0.f, a2 = 0.f, a3 = 0.f;
        #pragma unroll 4
        for (int m = 0; m < 128; ++m) {
            const int s = jj * 128 + m;
            const float4 R = sR[s];
            const float  f = sF[s];
            const float* p = Te + (size_t)sI[s] * 100;
            const float v0 = p[0], v1 = p[100];
            const float G = v0 + f * (v1 - v0);
            a0 += R.x * G; a1 += R.y * G; a2 += R.z * G; a3 += R.w * G;
        }
        atomicAdd(&sXYZ[g],       a0);
        atomicAdd(&sXYZ[100 + g], a1);
        atomicAdd(&sXYZ[200 + g], a2);
        atomicAdd(&sXYZ[300 + g], a3);
    }
    __syncthreads();

    const float inv = 1.0f / 65536.0f;
    _Float16* dr = DRh + (((size_t)i * 4 + b) * 256 + n) * FIT_IN;
    for (int q = t; q < 400; q += 256) {
        const int gg = q >> 2, h0 = (q & 3) * 4;
        ushort4 pk;
        _Float16* ph = (_Float16*)&pk;
        #pragma unroll
        for (int r = 0; r < 4; ++r) {
            const int h = h0 + r;
            const float v = (sXYZ[gg] * sXYZ[h] + sXYZ[100 + gg] * sXYZ[100 + h]
                           + sXYZ[200 + gg] * sXYZ[200 + h] + sXYZ[300 + gg] * sXYZ[300 + h]) * inv;
            ph[r] = (_Float16)v;
        }
        *(ushort4*)(dr + gg * 16 + h0) = pk;
    }
}

// ---------------------------------------------------------------------------
// k_fit: the ENTIRE fit MLP in one kernel. 256 blocks x 512 threads,
// 8 atom-rows per block:
//   h0 = tanh(DR @ W0 + b0)        K=1600, reg-prefetch dbuf LDS, 1 barrier/step
//   h1 = tanh(h0 @ W1 + b1) + h0   K=240 (padded 256)
//   h2 = tanh(h1 @ W2 + b2) + h1
//   out = h2 . W3 + b3
// No P workspace, no k-split, no inter-kernel round trips.
// MFMA 16x16x32 f16; verified layouts: A[m=lane&15][k=quad*8+j],
// B[k=quad*8+j][n=lane&15], D[row=quad*4+reg][col=lane&15].
// ---------------------------------------------------------------------------
__global__ __launch_bounds__(512) void k_fit(
    const _Float16* __restrict__ DRh,
    const _Float16* __restrict__ W0T, const _Float16* __restrict__ W1T,
    const _Float16* __restrict__ W2T,
    const float* __restrict__ fb0, const float* __restrict__ fb1,
    const float* __restrict__ fb2, const float* __restrict__ fW3,
    const float* __restrict__ fb3, float* __restrict__ out)
{
    __shared__ _Float16 sB[2][240 * 40];   // B tile dbuf [n][k], stride 40
    __shared__ _Float16 sA0[2][16 * 40];   // layer-0 A tile dbuf (rows 8..15 zero)
    __shared__ _Float16 sA[16 * 264];      // h f16 operand, k padded to 256
    __shared__ float    hRes[2][8 * 240];  // f32 h ping-pong (residual)

    const int t    = threadIdx.x;
    const int w    = t >> 6;               // 0..7
    const int lane = t & 63;
    const int ln   = lane & 15;
    const int quad = lane >> 4;
    const int r0   = blockIdx.x * 8;       // 0..2040
    const int tp   = r0 >> 10;
    const int nf0  = w * 2;
    const int nfr  = (w < 7) ? 2 : 1;      // 15 n-frags over 8 waves

    // zero sA (covers rows 8..15 and k-pad cols) and sA0 (rows 8..15 stay 0)
    for (int q = t; q < 16 * 264; q += 512) sA[q] = (_Float16)0.f;
    for (int q = t; q < 2 * 16 * 40; q += 512) ((_Float16*)sA0)[q] = (_Float16)0.f;

    const _Float16* Ab = DRh + (size_t)r0 * FIT_IN;
    const _Float16* Wb = W0T + (size_t)tp * 240 * FIT_IN;

    // ---------------- layer 0: K=1600, 50 k-steps ----------------
    f4v acc[2];
    acc[0] = (f4v)0.f; acc[1] = (f4v)0.f;
    {
        uint2 pB[4]; uint2 pA;
        // prefetch step 0
        {
            const int k0 = 0;
            #pragma unroll
            for (int j = 0; j < 4; ++j) {
                const int q = t + j * 512;
                if (q < 1920) {
                    const int n = q >> 3, kq = (q & 7) * 4;
                    pB[j] = *(const uint2*)(Wb + (size_t)n * FIT_IN + k0 + kq);
                }
            }
            if (t < 64) {
                const int m = t >> 3, kq = (t & 7) * 4;
                pA = *(const uint2*)(Ab + (size_t)m * FIT_IN + k0 + kq);
            }
        }
        for (int step = 0; step < 50; ++step) {
            const int buf = step & 1;
            // write staged regs to LDS
            #pragma unroll
            for (int j = 0; j < 4; ++j) {
                const int q = t + j * 512;
                if (q < 1920) {
                    const int n = q >> 3, kq = (q & 7) * 4;
                    *(uint2*)&sB[buf][n * 40 + kq] = pB[j];
                }
            }
            if (t < 64) {
                const int m = t >> 3, kq = (t & 7) * 4;
                *(uint2*)&sA0[buf][m * 40 + kq] = pA;
            }
            __syncthreads();
            // issue next-step loads (latency hides under MFMA phase)
            if (step < 49) {
                const int k0 = (step + 1) * 32;
                #pragma unroll
                for (int j = 0; j < 4; ++j) {
                    const int q = t + j * 512;
                    if (q < 1920) {
                        const int n = q >> 3, kq = (q & 7) * 4;
                        pB[j] = *(const uint2*)(Wb + (size_t)n * FIT_IN + k0 + kq);
                    }
                }
                if (t < 64) {
                    const int m = t >> 3, kq = (t & 7) * 4;
                    pA = *(const uint2*)(Ab + (size_t)m * FIT_IN + k0 + kq);
                }
            }
            const h8 afr = *(const h8*)&sA0[buf][ln * 40 + quad * 8];
            #pragma unroll
            for (int nf = 0; nf < 2; ++nf) {
                if (nf < nfr) {
                    const h8 bfr = *(const h8*)&sB[buf][((nf0 + nf) * 16 + ln) * 40 + quad * 8];
                    acc[nf] = __builtin_amdgcn_mfma_f32_16x16x32_f16(afr, bfr, acc[nf], 0, 0, 0);
                }
            }
            // NOTE: single barrier per step — next step writes buf^1, and each
            // wave's LDS reads are drained (lgkmcnt 0) at the next barrier
            // before buf is rewritten at step+2.
        }
    }
    __syncthreads();
    // epilogue 0: acc -> h0 (rows 0..7 live in quads 0,1)
    {
        const float* B0 = fb0 + tp * FH;
        #pragma unroll
        for (int nf = 0; nf < 2; ++nf) {
            if (nf < nfr && quad < 2) {
                const int col = (nf0 + nf) * 16 + ln;
                const float bias = B0[col];
                #pragma unroll
                for (int r = 0; r < 4; ++r) {
                    const int m = quad * 4 + r;
                    const float v = fast_tanh(acc[nf][r] + bias);
                    hRes[0][m * 240 + col] = v;
                    sA[m * 264 + col] = (_Float16)v;
                }
            }
        }
    }
    __syncthreads();

    // ---------------- layers 1,2: K=240 (pad 256), 8 k-steps ----------------
    for (int layer = 0; layer < 2; ++layer) {
        const _Float16* Wt = (layer == 0 ? W1T : W2T) + (size_t)tp * FH * FH;
        const float* Bias  = (layer == 0 ? fb1 : fb2) + tp * FH;
        const float* res   = hRes[layer];
        float* outb        = hRes[layer ^ 1];

        f4v a2[2];
        a2[0] = (f4v)0.f; a2[1] = (f4v)0.f;
        uint2 pW[4];
        // prefetch step 0
        #pragma unroll
        for (int j = 0; j < 4; ++j) {
            const int q = t + j * 512;
            if (q < 1920) {
                const int n = q >> 3, kq = (q & 7) * 4;
                pW[j] = (kq < FH) ? *(const uint2*)(Wt + (size_t)n * FH + kq)
                                  : make_uint2(0u, 0u);
            }
        }
        for (int step = 0; step < 8; ++step) {
            const int buf = step & 1;
            #pragma unroll
            for (int j = 0; j < 4; ++j) {
                const int q = t + j * 512;
                if (q < 1920) {
                    const int n = q >> 3, kq = (q & 7) * 4;
                    *(uint2*)&sB[buf][n * 40 + kq] = pW[j];
                }
            }
            __syncthreads();
            if (step < 7) {
                const int k0 = (step + 1) * 32;
                #pragma unroll
                for (int j = 0; j < 4; ++j) {
                    const int q = t + j * 512;
                    if (q < 1920) {
                        const int n = q >> 3, kq = (q & 7) * 4;
                        const int k = k0 + kq;
                        pW[j] = (k < FH) ? *(const uint2*)(Wt + (size_t)n * FH + k)
                                         : make_uint2(0u, 0u);
                    }
                }
            }
            const int k0 = step * 32;
            const h8 afr = *(const h8*)&sA[ln * 264 + k0 + quad * 8];
            #pragma unroll
            for (int nf = 0; nf < 2; ++nf) {
                if (nf < nfr) {
                    const h8 bfr = *(const h8*)&sB[buf][((nf0 + nf) * 16 + ln) * 40 + quad * 8];
                    a2[nf] = __builtin_amdgcn_mfma_f32_16x16x32_f16(afr, bfr, a2[nf], 0, 0, 0);
                }
            }
        }
        __syncthreads();    // drain sA reads before epilogue rewrites sA
        #pragma unroll
        for (int nf = 0; nf < 2; ++nf) {
            if (nf < nfr && quad < 2) {
                const int col = (nf0 + nf) * 16 + ln;
                const float bias = Bias[col];
                #pragma unroll
                for (int r = 0; r < 4; ++r) {
                    const int m = quad * 4 + r;
                    const float v = fast_tanh(a2[nf][r] + bias) + res[m * 240 + col];
                    outb[m * 240 + col] = v;
                    if (layer == 0) sA[m * 264 + col] = (_Float16)v;
                }
            }
        }
        __syncthreads();    // outb/sA visible before next layer / out phase
    }

    // ---------------- out: row w per wave, h2 in hRes[0] ----------------
    {
        const float* h2 = hRes[0];
        const float* wv = fW3 + tp * FH;
        const int m = w;
        float s = 0.f;
        #pragma unroll
        for (int k = lane; k < FH; k += 64) s += h2[m * 240 + k] * wv[k];
        #pragma unroll
        for (int off = 32; off > 0; off >>= 1) s += __shfl_down(s, off);
        if (lane == 0) {
            const int gr = r0 + m;
            const int rem = gr & 1023;
            const int b = rem >> 8, n = rem & 255;
            out[b * 512 + tp * 256 + n] = s + fb3[tp];
        }
    }
}

// ---------------------------------------------------------------------------
extern "C" void kernel_launch(void* const* d_in, const int* in_sizes, int n_in,
                              void* d_out, int out_size, void* d_ws, size_t ws_size,
                              hipStream_t stream)
{
    const float* Ri  = (const float*)d_in[0];
    const float* eW0 = (const float*)d_in[1];
    const float* eB0 = (const float*)d_in[2];
    const float* eW1 = (const float*)d_in[3];
    const float* eB1 = (const float*)d_in[4];
    const float* eW2 = (const float*)d_in[5];
    const float* eB2 = (const float*)d_in[6];
    const float* fW0 = (const float*)d_in[7];
    const float* fb0 = (const float*)d_in[8];
    const float* fW1 = (const float*)d_in[9];
    const float* fb1 = (const float*)d_in[10];
    const float* fW2 = (const float*)d_in[11];
    const float* fb2 = (const float*)d_in[12];
    const float* fW3 = (const float*)d_in[13];
    const float* fb3 = (const float*)d_in[14];

    // workspace layout (bytes)
    char* p = (char*)d_ws;
    float* T   = (float*)p;                 p += (size_t)4 * NK * 100 * 4;        // 3.28 MB
    _Float16* DRh = (_Float16*)p;           p += (size_t)2048 * FIT_IN * 2;       // 6.55 MB
    _Float16* W0T = (_Float16*)p;           p += (size_t)768000 * 2;              // 1.54 MB
    _Float16* W1T = (_Float16*)p;           p += (size_t)115200 * 2;
    _Float16* W2T = (_Float16*)p;           p += (size_t)115200 * 2;

    k_prep<<<dim3(512), dim3(256), 0, stream>>>(eW0, eB0, eW1, eB1, eW2, eB2, T,
                                                fW0, fW1, fW2, W0T, W1T, W2T);
    k_xyz<<<dim3(2048), dim3(256), 0, stream>>>(Ri, T, DRh);
    k_fit<<<dim3(256), dim3(512), 0, stream>>>(DRh, W0T, W1T, W2T,
                                               fb0, fb1, fb2, fW3, fb3,
                                               (float*)d_out);
}

// Round 3
// 172.921 us; speedup vs baseline: 1.1374x; 1.0076x over previous
//
#include <hip/hip_runtime.h>
#include <hip/hip_bf16.h>

#define FH 240
#define FIT_IN 1600
#define NK 2048            // table knots per e
#define TLO -16.0f
#define TINVH 64.0f        // knots per unit S (h = 1/64)

typedef _Float16 h8 __attribute__((ext_vector_type(8)));
typedef float f4v __attribute__((ext_vector_type(4)));

__device__ __forceinline__ float fast_tanh(float x) {
    float e2 = __builtin_amdgcn_exp2f(x * 2.8853900817779268f);
    return 1.0f - 2.0f * __builtin_amdgcn_rcpf(e2 + 1.0f);
}

#define FMA_ROW(r, s) \
    acc[r][0] += (s) * b0.x; acc[r][1] += (s) * b0.y; \
    acc[r][2] += (s) * b0.z; acc[r][3] += (s) * b0.w; \
    acc[r][4] += (s) * b1.x; acc[r][5] += (s) * b1.y; \
    acc[r][6] += (s) * b1.z; acc[r][7] += (s) * b1.w;

// ---------------------------------------------------------------------------
// k_prep: blocks 0..63 build the embedding table; blocks 64..511 convert
// fit weights to f16 transposed WT[tp][n][k]. (unchanged)
// ---------------------------------------------------------------------------
#define TOFF_W0   0
#define TOFF_B0   28
#define TOFF_B1   56
#define TOFF_B2   108
#define TOFF_W1   208
#define TOFF_W2   1508
#define TOFF_H0T  6708
#define TOFF_H1T  10008
#define TSMEM     16608

__global__ __launch_bounds__(256) void k_prep(
    const float* __restrict__ eW0, const float* __restrict__ eB0,
    const float* __restrict__ eW1, const float* __restrict__ eB1,
    const float* __restrict__ eW2, const float* __restrict__ eB2,
    float* __restrict__ T,
    const float* __restrict__ fW0, const float* __restrict__ fW1,
    const float* __restrict__ fW2,
    _Float16* __restrict__ W0T, _Float16* __restrict__ W1T,
    _Float16* __restrict__ W2T)
{
    __shared__ float sm[TSMEM];
    const int t = threadIdx.x;

    if (blockIdx.x >= 64) {
        const int bid0 = blockIdx.x - 64;
        const int total = 768000 + 115200 + 115200;
        for (int idx = bid0 * 256 + t; idx < total; idx += 448 * 256) {
            if (idx < 768000) {
                const int tp = idx / 384000, r = idx - tp * 384000;
                const int n = r / 1600, k = r - n * 1600;
                W0T[idx] = (_Float16)fW0[tp * 384000 + k * 240 + n];
            } else if (idx < 883200) {
                const int j = idx - 768000;
                const int tp = j / 57600, r = j - tp * 57600;
                const int n = r / 240, k = r - n * 240;
                W1T[j] = (_Float16)fW1[tp * 57600 + k * 240 + n];
            } else {
                const int j = idx - 883200;
                const int tp = j / 57600, r = j - tp * 57600;
                const int n = r / 240, k = r - n * 240;
                W2T[j] = (_Float16)fW2[tp * 57600 + k * 240 + n];
            }
        }
        return;
    }

    const int w    = t >> 6;
    const int lane = t & 63;
    const int mi   = lane & 7;
    const int gi   = lane >> 3;
    const int mrow = w * 32 + mi * 4;

    const int e  = blockIdx.x >> 4;
    const int k0 = (blockIdx.x & 15) * 128;

    for (int idx = t; idx < 1250; idx += 256) {
        int k = idx / 50, g = idx - k * 50;
        sm[TOFF_W1 + k * 52 + g] = eW1[e * 1250 + idx];
    }
    for (int idx = t; idx < 5000; idx += 256) {
        int k = idx / 100, r = idx - k * 100;
        int half = r / 50, g = r - half * 50;
        sm[TOFF_W2 + k * 104 + half * 52 + g] = eW2[e * 5000 + idx];
    }
    if (t < 25)       { sm[TOFF_W0 + t] = eW0[e * 25 + t]; sm[TOFF_B0 + t] = eB0[e * 25 + t]; }
    else if (t < 75)  { sm[TOFF_B1 + (t - 25)] = eB1[e * 50 + (t - 25)]; }
    else if (t < 175) { sm[TOFF_B2 + (t - 75)] = eB2[e * 100 + (t - 75)]; }
    __syncthreads();

    if (t < 128) {
        const float S = TLO + (float)(k0 + t) * (1.0f / TINVH);
        #pragma unroll
        for (int k = 0; k < 25; ++k)
            sm[TOFF_H0T + k * 132 + t] = fast_tanh(S * sm[TOFF_W0 + k] + sm[TOFF_B0 + k]);
    }
    __syncthreads();

    {
        float acc[4][8];
        #pragma unroll
        for (int r = 0; r < 4; ++r)
            #pragma unroll
            for (int c = 0; c < 8; ++c) acc[r][c] = 0.f;

        #pragma unroll 5
        for (int k = 0; k < 25; ++k) {
            const float4 av = *(const float4*)&sm[TOFF_H0T + k * 132 + mrow];
            const float4 b0 = *(const float4*)&sm[TOFF_W1 + k * 52 + gi * 8];
            const float4 b1 = *(const float4*)&sm[TOFF_W1 + k * 52 + gi * 8 + 4];
            FMA_ROW(0, av.x) FMA_ROW(1, av.y) FMA_ROW(2, av.z) FMA_ROW(3, av.w)
        }
        #pragma unroll
        for (int c = 0; c < 8; ++c) {
            const int g = gi * 8 + c;
            if (g < 50) {
                const int gm = (g < 25) ? g : g - 25;
                const float4 h0r = *(const float4*)&sm[TOFF_H0T + gm * 132 + mrow];
                const float bias = sm[TOFF_B1 + g];
                float4 o;
                o.x = fast_tanh(acc[0][c] + bias) + h0r.x;
                o.y = fast_tanh(acc[1][c] + bias) + h0r.y;
                o.z = fast_tanh(acc[2][c] + bias) + h0r.z;
                o.w = fast_tanh(acc[3][c] + bias) + h0r.w;
                *(float4*)&sm[TOFF_H1T + g * 132 + mrow] = o;
            }
        }
    }
    __syncthreads();

    for (int half = 0; half < 2; ++half) {
        float acc[4][8];
        #pragma unroll
        for (int r = 0; r < 4; ++r)
            #pragma unroll
            for (int c = 0; c < 8; ++c) acc[r][c] = 0.f;

        #pragma unroll 5
        for (int k = 0; k < 50; ++k) {
            const float4 av = *(const float4*)&sm[TOFF_H1T + k * 132 + mrow];
            const float4 b0 = *(const float4*)&sm[TOFF_W2 + k * 104 + half * 52 + gi * 8];
            const float4 b1 = *(const float4*)&sm[TOFF_W2 + k * 104 + half * 52 + gi * 8 + 4];
            FMA_ROW(0, av.x) FMA_ROW(1, av.y) FMA_ROW(2, av.z) FMA_ROW(3, av.w)
        }
        #pragma unroll
        for (int c = 0; c < 8; ++c) {
            const int g = gi * 8 + c;
            if (g < 50) {
                const float4 h1r = *(const float4*)&sm[TOFF_H1T + g * 132 + mrow];
                const float bias = sm[TOFF_B2 + half * 50 + g];
                float* out = T + ((size_t)e * NK + k0 + mrow) * 100 + half * 50 + g;
                out[0]   = fast_tanh(acc[0][c] + bias) + h1r.x;
                out[100] = fast_tanh(acc[1][c] + bias) + h1r.y;
                out[200] = fast_tanh(acc[2][c] + bias) + h1r.z;
                out[300] = fast_tanh(acc[3][c] + bias) + h1r.w;
            }
        }
    }
}

// ---------------------------------------------------------------------------
// k_xyz: per atom: gather+lerp G from table, reduce xyz[c][g], emit DR (f16).
// (unchanged — proven)
// ---------------------------------------------------------------------------
__global__ __launch_bounds__(256) void k_xyz(
    const float* __restrict__ Ri, const float* __restrict__ T,
    _Float16* __restrict__ DRh)
{
    __shared__ float4 sR[256];
    __shared__ float  sF[256];
    __shared__ int    sI[256];
    __shared__ float  sXYZ[400];

    const int t   = threadIdx.x;
    const int blk = blockIdx.x;          // 0..2047
    const int b   = blk >> 9;
    const int i   = (blk >> 8) & 1;
    const int n   = blk & 255;

    for (int idx = t; idx < 400; idx += 256) sXYZ[idx] = 0.f;

    {
        const int jj = t >> 7, m = t & 127;
        const size_t row = ((size_t)(b * 512 + i * 256 + n)) * 256 + jj * 128 + m;
        const float4 r = *(const float4*)(Ri + row * 4);
        sR[t] = r;
        float u = (r.x - TLO) * TINVH;
        int ii = (int)u;
        ii = (ii < 0) ? 0 : ((ii > NK - 2) ? NK - 2 : ii);
        sI[t] = ii;
        sF[t] = u - (float)ii;
    }
    __syncthreads();

    const int jj = t >> 7;
    const int g  = t & 127;
    if (g < 100) {
        const float* Te = T + ((size_t)(i * 2 + jj)) * NK * 100 + g;
        float a0 = 0.f, a1 = 0.f, a2 = 0.f, a3 = 0.f;
        #pragma unroll 4
        for (int m = 0; m < 128; ++m) {
            const int s = jj * 128 + m;
            const float4 R = sR[s];
            const float  f = sF[s];
            const float* p = Te + (size_t)sI[s] * 100;
            const float v0 = p[0], v1 = p[100];
            const float G = v0 + f * (v1 - v0);
            a0 += R.x * G; a1 += R.y * G; a2 += R.z * G; a3 += R.w * G;
        }
        atomicAdd(&sXYZ[g],       a0);
        atomicAdd(&sXYZ[100 + g], a1);
        atomicAdd(&sXYZ[200 + g], a2);
        atomicAdd(&sXYZ[300 + g], a3);
    }
    __syncthreads();

    const float inv = 1.0f / 65536.0f;
    _Float16* dr = DRh + (((size_t)i * 4 + b) * 256 + n) * FIT_IN;
    for (int q = t; q < 400; q += 256) {
        const int gg = q >> 2, h0 = (q & 3) * 4;
        ushort4 pk;
        _Float16* ph = (_Float16*)&pk;
        #pragma unroll
        for (int r = 0; r < 4; ++r) {
            const int h = h0 + r;
            const float v = (sXYZ[gg] * sXYZ[h] + sXYZ[100 + gg] * sXYZ[100 + h]
                           + sXYZ[200 + gg] * sXYZ[200 + h] + sXYZ[300 + gg] * sXYZ[300 + h]) * inv;
            ph[r] = (_Float16)v;
        }
        *(ushort4*)(dr + gg * 16 + h0) = pk;
    }
}

// ---------------------------------------------------------------------------
// k_fit: entire fit MLP, one kernel, 256 blocks x 512 threads, 8 rows/block.
// KEY CHANGE vs R2: MFMA operands stream DIRECTLY from global (L1/L2) into
// VGPRs — B-fragment B[k=quad*8+j][n=ln] is a contiguous 16B per-lane load
// from WT[n][k]; A rows are L1-resident. Layer 0 has ZERO LDS traffic and
// ZERO barriers (was 50 barriers + 15KB/step LDS round-trip). Layers 1/2
// keep only sA (h crosses waves), B direct from L2, 2 barriers each.
// MFMA 16x16x32 f16; layouts: A[m=lane&15][k=quad*8+j],
// B[k=quad*8+j][n=lane&15], D[row=quad*4+reg][col=lane&15].
// ---------------------------------------------------------------------------
__global__ __launch_bounds__(512) void k_fit(
    const _Float16* __restrict__ DRh,
    const _Float16* __restrict__ W0T, const _Float16* __restrict__ W1T,
    const _Float16* __restrict__ W2T,
    const float* __restrict__ fb0, const float* __restrict__ fb1,
    const float* __restrict__ fb2, const float* __restrict__ fW3,
    const float* __restrict__ fb3, float* __restrict__ out)
{
    __shared__ _Float16 sA[16 * 264];      // h f16 operand, k padded to 256 (zeros)
    __shared__ float    hRes[2][8 * 240];  // f32 h ping-pong (residual)

    const int t    = threadIdx.x;
    const int w    = t >> 6;               // 0..7
    const int lane = t & 63;
    const int ln   = lane & 15;
    const int quad = lane >> 4;
    const int r0   = blockIdx.x * 8;       // 0..2040
    const int tp   = r0 >> 10;
    const int nf0  = w * 2;
    const int nfr  = (w < 7) ? 2 : 1;      // 15 n-frags over 8 waves

    // zero sA (covers rows 8..15 and k-pad cols 240..263)
    for (int q = t; q < 16 * 264; q += 512) sA[q] = (_Float16)0.f;

    // ---------------- layer 0: K=1600, 50 k-steps, no LDS, no barriers ------
    f4v acc[2];
    acc[0] = (f4v)0.f; acc[1] = (f4v)0.f;
    {
        // A: rows 8..15 of the MFMA M-dim alias rows 0..7 (discarded in D).
        const _Float16* Arow = DRh + (size_t)(r0 + (ln & 7)) * FIT_IN;
        const _Float16* W0b  = W0T + (size_t)tp * 240 * FIT_IN;
        const _Float16* Bp0  = W0b + (size_t)(nf0 * 16 + ln) * FIT_IN;
        const _Float16* Bp1  = W0b + (size_t)(((nfr > 1) ? nf0 + 1 : nf0) * 16 + ln) * FIT_IN;
        const int kq = quad * 8;

        // 2-deep software pipeline
        h8 a_c  = *(const h8*)(Arow + kq);
        h8 b0_c = *(const h8*)(Bp0 + kq);
        h8 b1_c = *(const h8*)(Bp1 + kq);
        h8 a_n  = *(const h8*)(Arow + 32 + kq);
        h8 b0_n = *(const h8*)(Bp0 + 32 + kq);
        h8 b1_n = *(const h8*)(Bp1 + 32 + kq);

        #pragma unroll 2
        for (int s = 0; s < 50; ++s) {
            h8 a_f, b0_f, b1_f;
            if (s + 2 < 50) {
                const int k2 = (s + 2) * 32 + kq;
                a_f  = *(const h8*)(Arow + k2);
                b0_f = *(const h8*)(Bp0 + k2);
                b1_f = *(const h8*)(Bp1 + k2);
            }
            acc[0] = __builtin_amdgcn_mfma_f32_16x16x32_f16(a_c, b0_c, acc[0], 0, 0, 0);
            acc[1] = __builtin_amdgcn_mfma_f32_16x16x32_f16(a_c, b1_c, acc[1], 0, 0, 0);
            a_c = a_n;  b0_c = b0_n;  b1_c = b1_n;
            a_n = a_f;  b0_n = b0_f;  b1_n = b1_f;
        }
    }
    // epilogue 0: acc -> h0 (valid rows live in quads 0,1)
    {
        const float* B0 = fb0 + tp * FH;
        #pragma unroll
        for (int nf = 0; nf < 2; ++nf) {
            if (nf < nfr && quad < 2) {
                const int col = (nf0 + nf) * 16 + ln;
                const float bias = B0[col];
                #pragma unroll
                for (int r = 0; r < 4; ++r) {
                    const int m = quad * 4 + r;
                    const float v = fast_tanh(acc[nf][r] + bias);
                    hRes[0][m * 240 + col] = v;
                    sA[m * 264 + col] = (_Float16)v;
                }
            }
        }
    }
    __syncthreads();

    // ---------------- layers 1,2: K=240 (pad 256), 8 k-steps ----------------
    for (int layer = 0; layer < 2; ++layer) {
        const _Float16* Wt = (layer == 0 ? W1T : W2T) + (size_t)tp * FH * FH;
        const float* Bias  = (layer == 0 ? fb1 : fb2) + tp * FH;
        const float* res   = hRes[layer];
        float* outb        = hRes[layer ^ 1];

        const _Float16* Bq0 = Wt + (size_t)(nf0 * 16 + ln) * FH;
        const _Float16* Bq1 = Wt + (size_t)(((nfr > 1) ? nf0 + 1 : nf0) * 16 + ln) * FH;
        const int kq = quad * 8;
        // NOTE: steps 7's k=224..255 B-loads run past row end into the next
        // row/array (mapped ws memory); sA k-columns >=240 are zero, so the
        // garbage contributes 0 to the MFMA.

        f4v a2[2];
        a2[0] = (f4v)0.f; a2[1] = (f4v)0.f;

        h8 b0_c = *(const h8*)(Bq0 + kq);
        h8 b1_c = *(const h8*)(Bq1 + kq);
        #pragma unroll
        for (int s = 0; s < 8; ++s) {
            h8 b0_n, b1_n;
            if (s + 1 < 8) {
                const int k1 = (s + 1) * 32 + kq;
                b0_n = *(const h8*)(Bq0 + k1);
                b1_n = *(const h8*)(Bq1 + k1);
            }
            const h8 afr = *(const h8*)&sA[ln * 264 + s * 32 + kq];
            a2[0] = __builtin_amdgcn_mfma_f32_16x16x32_f16(afr, b0_c, a2[0], 0, 0, 0);
            a2[1] = __builtin_amdgcn_mfma_f32_16x16x32_f16(afr, b1_c, a2[1], 0, 0, 0);
            b0_c = b0_n;  b1_c = b1_n;
        }
        __syncthreads();    // all sA reads drained before epilogue rewrites sA
        #pragma unroll
        for (int nf = 0; nf < 2; ++nf) {
            if (nf < nfr && quad < 2) {
                const int col = (nf0 + nf) * 16 + ln;
                const float bias = Bias[col];
                #pragma unroll
                for (int r = 0; r < 4; ++r) {
                    const int m = quad * 4 + r;
                    const float v = fast_tanh(a2[nf][r] + bias) + res[m * 240 + col];
                    outb[m * 240 + col] = v;
                    if (layer == 0) sA[m * 264 + col] = (_Float16)v;
                }
            }
        }
        __syncthreads();    // outb/sA visible before next layer / out phase
    }

    // ---------------- out: row w per wave, h2 in hRes[0] ----------------
    {
        const float* h2 = hRes[0];
        const float* wv = fW3 + tp * FH;
        const int m = w;
        float s = 0.f;
        #pragma unroll
        for (int k = lane; k < FH; k += 64) s += h2[m * 240 + k] * wv[k];
        #pragma unroll
        for (int off = 32; off > 0; off >>= 1) s += __shfl_down(s, off);
        if (lane == 0) {
            const int gr = r0 + m;
            const int rem = gr & 1023;
            const int b = rem >> 8, n = rem & 255;
            out[b * 512 + tp * 256 + n] = s + fb3[tp];
        }
    }
}

// ---------------------------------------------------------------------------
extern "C" void kernel_launch(void* const* d_in, const int* in_sizes, int n_in,
                              void* d_out, int out_size, void* d_ws, size_t ws_size,
                              hipStream_t stream)
{
    const float* Ri  = (const float*)d_in[0];
    const float* eW0 = (const float*)d_in[1];
    const float* eB0 = (const float*)d_in[2];
    const float* eW1 = (const float*)d_in[3];
    const float* eB1 = (const float*)d_in[4];
    const float* eW2 = (const float*)d_in[5];
    const float* eB2 = (const float*)d_in[6];
    const float* fW0 = (const float*)d_in[7];
    const float* fb0 = (const float*)d_in[8];
    const float* fW1 = (const float*)d_in[9];
    const float* fb1 = (const float*)d_in[10];
    const float* fW2 = (const float*)d_in[11];
    const float* fb2 = (const float*)d_in[12];
    const float* fW3 = (const float*)d_in[13];
    const float* fb3 = (const float*)d_in[14];

    // workspace layout (bytes)
    char* p = (char*)d_ws;
    float* T   = (float*)p;                 p += (size_t)4 * NK * 100 * 4;        // 3.28 MB
    _Float16* DRh = (_Float16*)p;           p += (size_t)2048 * FIT_IN * 2;       // 6.55 MB
    _Float16* W0T = (_Float16*)p;           p += (size_t)768000 * 2;              // 1.54 MB
    _Float16* W1T = (_Float16*)p;           p += (size_t)115200 * 2;
    _Float16* W2T = (_Float16*)p;           p += (size_t)115200 * 2;

    k_prep<<<dim3(512), dim3(256), 0, stream>>>(eW0, eB0, eW1, eB1, eW2, eB2, T,
                                                fW0, fW1, fW2, W0T, W1T, W2T);
    k_xyz<<<dim3(2048), dim3(256), 0, stream>>>(Ri, T, DRh);
    k_fit<<<dim3(256), dim3(512), 0, stream>>>(DRh, W0T, W1T, W2T,
                                               fb0, fb1, fb2, fW3, fb3,
                                               (float*)d_out);
}